// Round 6
// baseline (275.438 us; speedup 1.0000x reference)
//
#include <hip/hip_runtime.h>

typedef __bf16 bf16_t;
typedef __bf16 bf16x4 __attribute__((ext_vector_type(4)));
typedef __bf16 bf16x8 __attribute__((ext_vector_type(8)));
typedef float f32x4 __attribute__((ext_vector_type(4)));

#define MFMA16(a, b, c) __builtin_amdgcn_mfma_f32_16x16x32_bf16(a, b, c, 0, 0, 0)
#define LOG2E 1.4426950408889634f
#define SHIFT 16.0f

// async global -> LDS, 16B per lane (LDS dest = wave-uniform base + lane*16)
#define GLL(g, l)                                                      \
  __builtin_amdgcn_global_load_lds(                                    \
      (const __attribute__((address_space(1))) void*)(g),              \
      (__attribute__((address_space(3))) void*)(l), 16, 0, 0)

static constexpr int NB = 2;
static constexpr int SEQ = 4096;
static constexpr int DM = 512;
static constexpr int NH = 8;
static constexpr int HD = 64;
static constexpr int M_ROWS = NB * SEQ;  // 8192

// ---------------------------------------------------------------------------
// Weights fp32 -> bf16
// ---------------------------------------------------------------------------
__global__ __launch_bounds__(256) void cvt_w_kernel(
    const float* __restrict__ w0, const float* __restrict__ w1,
    const float* __restrict__ w2, const float* __restrict__ w3,
    bf16_t* __restrict__ out) {
  const float* src = (blockIdx.y == 0) ? w0 : (blockIdx.y == 1) ? w1
                   : (blockIdx.y == 2) ? w2 : w3;
  int i = (blockIdx.x * 256 + threadIdx.x) * 4;
  float4 v = *(const float4*)(src + i);
  bf16_t* o = out + blockIdx.y * (DM * DM) + i;
  o[0] = (bf16_t)v.x; o[1] = (bf16_t)v.y; o[2] = (bf16_t)v.z; o[3] = (bf16_t)v.w;
}

// ---------------------------------------------------------------------------
// GEMM body: Out = (X @ W^T + bias) * scale.  Tile TM x 128, BK=64.
// XOR-swizzled LDS (16B chunks, phys = ch ^ (row&7)); B staged via GLL-16;
// A staged via GLL (bf16, XMODE 1) or fused fp32->bf16 convert (XMODE 0,
// TM must be 128). 32 MFMA per wave per K-step, 8 K-steps.
// omode 0: bf16 [bh][s][64]; 1: bf16 [bh][d][s]; 2: fp32 [m][512].
// ---------------------------------------------------------------------------
template <int XMODE, int TM>
__device__ __forceinline__ void gemm_body(
    const void* __restrict__ Xv, const bf16_t* __restrict__ Wm,
    const float* __restrict__ bias, void* __restrict__ Out,
    int omode, float scale) {
  constexpr int MB = TM / 32;  // m-frags per wave
  __shared__ bf16_t Asm[TM * 64];
  __shared__ bf16_t Bsm[128 * 64];

  const int tid = threadIdx.x;
  const int w = tid >> 6;
  const int lane = tid & 63;
  const int quad = lane >> 4, l15 = lane & 15;
  const int l8 = lane >> 3;
  const int swcol = ((lane & 7) ^ l8) * 8;  // swizzled col (elems) for staging
  const int m0 = blockIdx.x * TM;
  const int n0 = blockIdx.y * 128;
  const int moff = (w & 1) * (TM / 2);
  const int noff = (w >> 1) * 64;

  f32x4 acc[MB][4];
#pragma unroll
  for (int mb = 0; mb < MB; mb++)
#pragma unroll
    for (int nb = 0; nb < 4; nb++) { acc[mb][nb][0] = 0.f; acc[mb][nb][1] = 0.f; acc[mb][nb][2] = 0.f; acc[mb][nb][3] = 0.f; }

  for (int k0 = 0; k0 < DM; k0 += 64) {
    __syncthreads();
    // ---- stage B (weights) 128x64: 4 GLL rounds ----
#pragma unroll
    for (int j = 0; j < 4; j++) {
      const int row = j * 32 + w * 8 + l8;
      GLL(Wm + (size_t)(n0 + row) * DM + k0 + swcol, Bsm + (j * 256 + w * 64) * 8);
    }
    // ---- stage A ----
    if (XMODE == 1) {
#pragma unroll
      for (int j = 0; j < TM / 32; j++) {
        const int row = j * 32 + w * 8 + l8;
        GLL((const bf16_t*)Xv + (size_t)(m0 + row) * DM + k0 + swcol,
            Asm + (j * 256 + w * 64) * 8);
      }
    } else {
      // fused fp32->bf16: thread t handles row t>>1, half (t&1)*32 elems
      const int arow = tid >> 1;
      const int ahalf = (tid & 1) * 32;
      const float* src = (const float*)Xv + (size_t)(m0 + arow) * DM + k0 + ahalf;
      const int chb = (tid & 1) * 4;
#pragma unroll
      for (int i = 0; i < 4; i++) {
        float4 lo = *(const float4*)(src + i * 8);
        float4 hi = *(const float4*)(src + i * 8 + 4);
        bf16x8 pk;
        pk[0] = (bf16_t)lo.x; pk[1] = (bf16_t)lo.y; pk[2] = (bf16_t)lo.z; pk[3] = (bf16_t)lo.w;
        pk[4] = (bf16_t)hi.x; pk[5] = (bf16_t)hi.y; pk[6] = (bf16_t)hi.z; pk[7] = (bf16_t)hi.w;
        *(bf16x8*)&Asm[arow * 64 + (((chb + i) ^ (arow & 7)) * 8)] = pk;
      }
    }
    __syncthreads();

    // ---- fragments + MFMA (swizzled reads: row&7 == l15&7) ----
#pragma unroll
    for (int kd = 0; kd < 2; kd++) {
      const int fch = ((kd * 4 + quad) ^ (l15 & 7)) * 8;
      bf16x8 bfr[4];
#pragma unroll
      for (int nb = 0; nb < 4; nb++)
        bfr[nb] = *(const bf16x8*)&Bsm[(noff + nb * 16 + l15) * 64 + fch];
#pragma unroll
      for (int mb = 0; mb < MB; mb++) {
        bf16x8 a = *(const bf16x8*)&Asm[(moff + mb * 16 + l15) * 64 + fch];
#pragma unroll
        for (int nb = 0; nb < 4; nb++) acc[mb][nb] = MFMA16(a, bfr[nb], acc[mb][nb]);
      }
    }
  }

  // ---- epilogue ----
#pragma unroll
  for (int nb = 0; nb < 4; nb++) {
    const int n = n0 + noff + nb * 16 + l15;
    const float bn = bias[n];
    const int h = n >> 6, dd = n & 63;
#pragma unroll
    for (int mb = 0; mb < MB; mb++) {
      const int mbase = m0 + moff + mb * 16 + quad * 4;
      const int bb = mbase >> 12, s = mbase & 4095;
      if (omode == 0) {
#pragma unroll
        for (int r = 0; r < 4; r++) {
          const float val = (acc[mb][nb][r] + bn) * scale;
          ((bf16_t*)Out)[(size_t)((bb * NH + h) * SEQ + s + r) * HD + dd] = (bf16_t)val;
        }
      } else if (omode == 1) {
        bf16x4 pk;
#pragma unroll
        for (int r = 0; r < 4; r++) pk[r] = (bf16_t)(acc[mb][nb][r] + bn);
        *(bf16x4*)&((bf16_t*)Out)[(((size_t)(bb * NH + h) * HD + dd) << 12) + s] = pk;
      } else {
#pragma unroll
        for (int r = 0; r < 4; r++)
          ((float*)Out)[(size_t)(mbase + r) * DM + n] = acc[mb][nb][r] + bn;
      }
    }
  }
}

// Fused QKV projection. Grid (64,4,3) = 768 blocks -> 3 blocks/CU.
__global__ __launch_bounds__(256, 3) void qkv_kernel(
    const float* __restrict__ q, const float* __restrict__ k,
    const float* __restrict__ v, const bf16_t* __restrict__ Wall,
    const float* __restrict__ bq, const float* __restrict__ bk,
    const float* __restrict__ bv, bf16_t* __restrict__ Qb,
    bf16_t* __restrict__ Kb, bf16_t* __restrict__ Vb, float qscale) {
  const int z = blockIdx.z;
  const float* X = (z == 0) ? q : (z == 1) ? k : v;
  const float* bias = (z == 0) ? bq : (z == 1) ? bk : bv;
  bf16_t* Out = (z == 0) ? Qb : (z == 1) ? Kb : Vb;
  gemm_body<0, 128>(X, Wall + (size_t)z * DM * DM, bias, Out,
                    (z == 2) ? 1 : 0, (z == 0) ? qscale : 1.0f);
}

// Output projection. Grid (128,4) = 512 blocks.
__global__ __launch_bounds__(256, 3) void oproj_kernel(
    const bf16_t* __restrict__ X, const bf16_t* __restrict__ Wm,
    const float* __restrict__ bias, float* __restrict__ Out) {
  gemm_body<1, 64>(X, Wm, bias, Out, 2, 1.0f);
}

// ---------------------------------------------------------------------------
// Flash attention v3: no K/V LDS staging, no loop barriers.
// Block = 64 q x bh; 4 waves own interleaved kk-quarters (32-kk tiles),
// loading K/V fragments directly global->VGPR (L2-resident). Fixed-shift
// softmax (p = exp2(s + rb - 16)) makes partial O/l plain sums; cross-wave
// tree-reduce through LDS at block end. P round-trips per-wave LDS only.
// Grid (64, 16).
// ---------------------------------------------------------------------------
__global__ __launch_bounds__(256, 2) void attn_kernel(
    const bf16_t* __restrict__ Qb, const bf16_t* __restrict__ Kb,
    const bf16_t* __restrict__ Vb, const float* __restrict__ rel_pos,
    bf16_t* __restrict__ attn_out) {
  // union: P staging (loop) / reduction buffers (end)
  __shared__ char smem[34816];  // max(4*64*40*2=20480, 16K+16K+1K=33792)
  const int tid = threadIdx.x;
  const int w = tid >> 6;
  const int lane = tid & 63;
  const int quad = lane >> 4, l15 = lane & 15;
  const int bh = blockIdx.y;
  const int b = bh >> 3, h = bh & 7;
  const int qlo = blockIdx.x * 64;

  bf16_t* Pw = (bf16_t*)smem + w * (64 * 40);
  float* redA = (float*)smem;          // 4096 f32 (after loop only)
  float* redB = redA + 4096;           // 4096 f32
  float* redL = redB + 4096;           // [4][64]

  const float rb0 = rel_pos[h * 5 + 0] * LOG2E;
  const float rb1 = rel_pos[h * 5 + 1] * LOG2E;
  const float rb2 = rel_pos[h * 5 + 2] * LOG2E;
  const float rb3 = rel_pos[h * 5 + 3] * LOG2E;
  const float rb4 = rel_pos[h * 5 + 4] * LOG2E;

  // Q fragments (B-operand), 64 q
  bf16x8 qf[4][2];
#pragma unroll
  for (int qb = 0; qb < 4; qb++)
#pragma unroll
    for (int kd = 0; kd < 2; kd++)
      qf[qb][kd] = *(const bf16x8*)(Qb + (size_t)(bh * SEQ + qlo + qb * 16 + l15) * HD + kd * 32 + 8 * quad);

  f32x4 o[4][4];   // [db][qb]
#pragma unroll
  for (int db = 0; db < 4; db++)
#pragma unroll
    for (int qb = 0; qb < 4; qb++) { o[db][qb][0] = 0.f; o[db][qb][1] = 0.f; o[db][qb][2] = 0.f; o[db][qb][3] = 0.f; }
  f32x4 l4[4];
#pragma unroll
  for (int qb = 0; qb < 4; qb++) { l4[qb][0] = 0.f; l4[qb][1] = 0.f; l4[qb][2] = 0.f; l4[qb][3] = 0.f; }

  bf16x8 ones;
#pragma unroll
  for (int i = 0; i < 8; i++) ones[i] = (bf16_t)1.0f;

  const bf16_t* Kbase = Kb + (size_t)bh * SEQ * HD;
  const bf16_t* Vbase = Vb + (((size_t)bh * HD) << 12);

  for (int t = 0; t < 32; t++) {
    const int kk0 = t * 128 + w * 32;  // this wave's 32-kk tile

    // ---- K/V fragments direct from global ----
    bf16x8 kA[2][2];
#pragma unroll
    for (int kkb = 0; kkb < 2; kkb++)
#pragma unroll
      for (int kd = 0; kd < 2; kd++)
        kA[kkb][kd] = *(const bf16x8*)(Kbase + (size_t)(kk0 + kkb * 16 + l15) * HD + kd * 32 + quad * 8);
    bf16x8 vA[4];
#pragma unroll
    for (int db = 0; db < 4; db++)
      vA[db] = *(const bf16x8*)(Vbase + (((size_t)(db * 16 + l15)) << 12) + kk0 + quad * 8);

    // ---- tile class: fold bias const + fixed shift into acc init ----
    float cini;
    bool nearband = false;
    if (kk0 >= qlo + 65) {
      cini = rb4 - SHIFT;
    } else if (kk0 + 33 <= qlo) {
      cini = rb0 - SHIFT;
    } else {
      cini = -SHIFT;
      nearband = true;
    }

    // ---- S^T = K·Q^T (C: row=kk local, col=q local) ----
    f32x4 s[2][4];
#pragma unroll
    for (int kkb = 0; kkb < 2; kkb++)
#pragma unroll
      for (int qb = 0; qb < 4; qb++) { s[kkb][qb][0] = cini; s[kkb][qb][1] = cini; s[kkb][qb][2] = cini; s[kkb][qb][3] = cini; }
#pragma unroll
    for (int kkb = 0; kkb < 2; kkb++)
#pragma unroll
      for (int qb = 0; qb < 4; qb++) {
        s[kkb][qb] = MFMA16(kA[kkb][0], qf[qb][0], s[kkb][qb]);
        s[kkb][qb] = MFMA16(kA[kkb][1], qf[qb][1], s[kkb][qb]);
      }

    if (nearband) {
#pragma unroll
      for (int kkb = 0; kkb < 2; kkb++)
#pragma unroll
        for (int qb = 0; qb < 4; qb++) {
          const int qg = qlo + qb * 16 + l15;
#pragma unroll
          for (int r = 0; r < 4; r++) {
            int dl = kk0 + kkb * 16 + quad * 4 + r - qg;
            float bias = dl <= -2 ? rb0
                       : (dl >= 2 ? rb4
                       : (dl == -1 ? rb1 : (dl == 0 ? rb2 : rb3)));
            s[kkb][qb][r] += bias;
          }
        }
    }

    // ---- p = exp2(s) -> P^T LDS (per-wave region, no barrier) ----
#pragma unroll
    for (int qb = 0; qb < 4; qb++) {
      bf16_t* Pr = &Pw[(qb * 16 + l15) * 40];
#pragma unroll
      for (int kkb = 0; kkb < 2; kkb++) {
        bf16x4 pk;
#pragma unroll
        for (int r = 0; r < 4; r++)
          pk[r] = (bf16_t)__builtin_amdgcn_exp2f(s[kkb][qb][r]);
        *(bf16x4*)&Pr[kkb * 16 + quad * 4] = pk;
      }
    }

    // ---- P fragments (B-operand), l via ones-MFMA, O^T += V^T·P^T ----
    bf16x8 pf[4];
#pragma unroll
    for (int qb = 0; qb < 4; qb++)
      pf[qb] = *(const bf16x8*)&Pw[(qb * 16 + l15) * 40 + quad * 8];
#pragma unroll
    for (int qb = 0; qb < 4; qb++) l4[qb] = MFMA16(ones, pf[qb], l4[qb]);
#pragma unroll
    for (int db = 0; db < 4; db++)
#pragma unroll
      for (int qb = 0; qb < 4; qb++)
        o[db][qb] = MFMA16(vA[db], pf[qb], o[db][qb]);
  }

  // ---- cross-wave tree reduce (fixed-shift partials are plain sums) ----
  __syncthreads();
  if (w == 2) {
#pragma unroll
    for (int db = 0; db < 4; db++)
#pragma unroll
      for (int qb = 0; qb < 4; qb++)
        *(f32x4*)&redA[((db * 4 + qb) * 64 + lane) * 4] = o[db][qb];
  }
  if (w == 3) {
#pragma unroll
    for (int db = 0; db < 4; db++)
#pragma unroll
      for (int qb = 0; qb < 4; qb++)
        *(f32x4*)&redB[((db * 4 + qb) * 64 + lane) * 4] = o[db][qb];
  }
  if (quad == 0) {
#pragma unroll
    for (int qb = 0; qb < 4; qb++) redL[w * 64 + qb * 16 + l15] = l4[qb][0];
  }
  __syncthreads();
  if (w == 0) {
#pragma unroll
    for (int db = 0; db < 4; db++)
#pragma unroll
      for (int qb = 0; qb < 4; qb++) {
        f32x4 tv = *(const f32x4*)&redA[((db * 4 + qb) * 64 + lane) * 4];
        o[db][qb][0] += tv[0]; o[db][qb][1] += tv[1]; o[db][qb][2] += tv[2]; o[db][qb][3] += tv[3];
      }
  }
  if (w == 1) {
#pragma unroll
    for (int db = 0; db < 4; db++)
#pragma unroll
      for (int qb = 0; qb < 4; qb++) {
        f32x4 tv = *(const f32x4*)&redB[((db * 4 + qb) * 64 + lane) * 4];
        o[db][qb][0] += tv[0]; o[db][qb][1] += tv[1]; o[db][qb][2] += tv[2]; o[db][qb][3] += tv[3];
      }
  }
  __syncthreads();
  if (w == 1) {
#pragma unroll
    for (int db = 0; db < 4; db++)
#pragma unroll
      for (int qb = 0; qb < 4; qb++)
        *(f32x4*)&redA[((db * 4 + qb) * 64 + lane) * 4] = o[db][qb];
  }
  __syncthreads();
  if (w == 0) {
#pragma unroll
    for (int db = 0; db < 4; db++)
#pragma unroll
      for (int qb = 0; qb < 4; qb++) {
        f32x4 tv = *(const f32x4*)&redA[((db * 4 + qb) * 64 + lane) * 4];
        o[db][qb][0] += tv[0]; o[db][qb][1] += tv[1]; o[db][qb][2] += tv[2]; o[db][qb][3] += tv[3];
      }
    // ---- epilogue: O^T / l_total ----
#pragma unroll
    for (int qb = 0; qb < 4; qb++) {
      const int q16 = qb * 16 + l15;
      const float lt = redL[q16] + redL[64 + q16] + redL[128 + q16] + redL[192 + q16];
      const float inv = 1.0f / lt;
      const int qg = qlo + q16;
#pragma unroll
      for (int db = 0; db < 4; db++) {
        bf16x4 pk;
#pragma unroll
        for (int r = 0; r < 4; r++) pk[r] = (bf16_t)(o[db][qb][r] * inv);
        *(bf16x4*)(attn_out + (size_t)(b * SEQ + qg) * DM + h * HD + db * 16 + quad * 4) = pk;
      }
    }
  }
}

// ---------------------------------------------------------------------------
extern "C" void kernel_launch(void* const* d_in, const int* in_sizes, int n_in,
                              void* d_out, int out_size, void* d_ws, size_t ws_size,
                              hipStream_t stream) {
  const float* q   = (const float*)d_in[0];
  const float* k   = (const float*)d_in[1];
  const float* v   = (const float*)d_in[2];
  const float* Wq  = (const float*)d_in[3];
  const float* bq  = (const float*)d_in[4];
  const float* Wk  = (const float*)d_in[5];
  const float* bk  = (const float*)d_in[6];
  const float* Wv  = (const float*)d_in[7];
  const float* bv  = (const float*)d_in[8];
  const float* Wo  = (const float*)d_in[9];
  const float* bo  = (const float*)d_in[10];
  const float* rel = (const float*)d_in[11];

  char* ws = (char*)d_ws;
  bf16_t* Wbf  = (bf16_t*)ws;                               // 2MB (4 matrices)
  bf16_t* Qbuf = (bf16_t*)(ws + (size_t)(2  << 20));        // 8MB [bh][s][64]
  bf16_t* Kbuf = (bf16_t*)(ws + (size_t)(10 << 20));        // 8MB [bh][s][64]
  bf16_t* Vbuf = (bf16_t*)(ws + (size_t)(18 << 20));        // 8MB [bh][d][s]
  bf16_t* Abuf = (bf16_t*)(ws + (size_t)(26 << 20));        // 8MB [b][s][512]

  cvt_w_kernel<<<dim3(256, 4), 256, 0, stream>>>(Wq, Wk, Wv, Wo, Wbf);

  const float qscale = LOG2E / 8.0f;  // fold 1/sqrt(64) + exp2 domain
  qkv_kernel<<<dim3(64, 4, 3), 256, 0, stream>>>(
      q, k, v, Wbf, bq, bk, bv, Qbuf, Kbuf, Vbuf, qscale);

  attn_kernel<<<dim3(64, 16), 256, 0, stream>>>(Qbuf, Kbuf, Vbuf, rel, Abuf);

  oproj_kernel<<<dim3(128, 4), 256, 0, stream>>>(Abuf, Wbf + 3 * DM * DM, bo, (float*)d_out);
}

// Round 7
// 240.842 us; speedup vs baseline: 1.1436x; 1.1436x over previous
//
#include <hip/hip_runtime.h>

typedef __bf16 bf16_t;
typedef __bf16 bf16x4 __attribute__((ext_vector_type(4)));
typedef __bf16 bf16x8 __attribute__((ext_vector_type(8)));
typedef float f32x4 __attribute__((ext_vector_type(4)));

#define MFMA16(a, b, c) __builtin_amdgcn_mfma_f32_16x16x32_bf16(a, b, c, 0, 0, 0)
#define LOG2E 1.4426950408889634f
#define SHIFT 16.0f

// async global -> LDS, 16B per lane (LDS dest = wave-uniform base + lane*16)
#define GLL(g, l)                                                      \
  __builtin_amdgcn_global_load_lds(                                    \
      (const __attribute__((address_space(1))) void*)(g),              \
      (__attribute__((address_space(3))) void*)(l), 16, 0, 0)

static constexpr int NB = 2;
static constexpr int SEQ = 4096;
static constexpr int DM = 512;
static constexpr int NH = 8;
static constexpr int HD = 64;
static constexpr int M_ROWS = NB * SEQ;  // 8192

// ---------------------------------------------------------------------------
// Weights fp32 -> bf16
// ---------------------------------------------------------------------------
__global__ __launch_bounds__(256) void cvt_w_kernel(
    const float* __restrict__ w0, const float* __restrict__ w1,
    const float* __restrict__ w2, const float* __restrict__ w3,
    bf16_t* __restrict__ out) {
  const float* src = (blockIdx.y == 0) ? w0 : (blockIdx.y == 1) ? w1
                   : (blockIdx.y == 2) ? w2 : w3;
  int i = (blockIdx.x * 256 + threadIdx.x) * 4;
  float4 v = *(const float4*)(src + i);
  bf16_t* o = out + blockIdx.y * (DM * DM) + i;
  o[0] = (bf16_t)v.x; o[1] = (bf16_t)v.y; o[2] = (bf16_t)v.z; o[3] = (bf16_t)v.w;
}

// ---------------------------------------------------------------------------
// GEMM v3: Out = (X @ W^T + bias) * scale. Tile 64x128, BK=64,
// DOUBLE-BUFFERED LDS, prefetch of step k+1 issued before step k's MFMAs
// (full compute-phase of load flight time), one barrier per K-step.
// XOR-swizzled LDS (16B chunks, phys = ch ^ (row&7)).
// omode 0: bf16 [bh][s][64]; 1: bf16 [bh][d][s]; 2: fp32 [m][512].
// ---------------------------------------------------------------------------
template <int XMODE>
__device__ __forceinline__ void gemm_body64(
    const void* __restrict__ Xv, const bf16_t* __restrict__ Wm,
    const float* __restrict__ bias, void* __restrict__ Out,
    int omode, float scale) {
  __shared__ bf16_t Asm[2][64 * 64];
  __shared__ bf16_t Bsm[2][128 * 64];

  const int tid = threadIdx.x;
  const int w = tid >> 6;
  const int lane = tid & 63;
  const int quad = lane >> 4, l15 = lane & 15;
  const int l8 = lane >> 3;
  const int swcol = ((lane & 7) ^ (l8 & 7)) * 8;  // swizzled source col
  const int m0 = blockIdx.x * 64;
  const int n0 = blockIdx.y * 128;
  const int moff = (w & 1) * 32;
  const int noff = (w >> 1) * 64;

  const bf16_t* Xb = (const bf16_t*)Xv;
  const float* Xf = (const float*)Xv;

  // fp32 A staging coords (XMODE 0): thread -> row tid>>2, 16-float segment
  const int arow = tid >> 2;
  const int aseg = (tid & 3) * 16;
  const int ach = (tid & 3) * 2;
  const int asw = arow & 7;

  f32x4 acc[2][4];
#pragma unroll
  for (int mb = 0; mb < 2; mb++)
#pragma unroll
    for (int nb = 0; nb < 4; nb++) { acc[mb][nb][0] = 0.f; acc[mb][nb][1] = 0.f; acc[mb][nb][2] = 0.f; acc[mb][nb][3] = 0.f; }

  // ---- stage K-step 0 into buffer 0 ----
#pragma unroll
  for (int j = 0; j < 4; j++) {
    const int row = j * 32 + w * 8 + l8;
    GLL(Wm + (size_t)(n0 + row) * DM + swcol, &Bsm[0][(j * 256 + w * 64) * 8]);
  }
  if (XMODE == 1) {
#pragma unroll
    for (int j = 0; j < 2; j++) {
      const int row = j * 32 + w * 8 + l8;
      GLL(Xb + (size_t)(m0 + row) * DM + swcol, &Asm[0][(j * 256 + w * 64) * 8]);
    }
  } else {
    const float* src = Xf + (size_t)(m0 + arow) * DM + aseg;
    float4 x0 = *(const float4*)(src);
    float4 x1 = *(const float4*)(src + 4);
    float4 x2 = *(const float4*)(src + 8);
    float4 x3 = *(const float4*)(src + 12);
    bf16x8 p0, p1;
    p0[0] = (bf16_t)x0.x; p0[1] = (bf16_t)x0.y; p0[2] = (bf16_t)x0.z; p0[3] = (bf16_t)x0.w;
    p0[4] = (bf16_t)x1.x; p0[5] = (bf16_t)x1.y; p0[6] = (bf16_t)x1.z; p0[7] = (bf16_t)x1.w;
    p1[0] = (bf16_t)x2.x; p1[1] = (bf16_t)x2.y; p1[2] = (bf16_t)x2.z; p1[3] = (bf16_t)x2.w;
    p1[4] = (bf16_t)x3.x; p1[5] = (bf16_t)x3.y; p1[6] = (bf16_t)x3.z; p1[7] = (bf16_t)x3.w;
    *(bf16x8*)&Asm[0][arow * 64 + ((ach ^ asw) * 8)] = p0;
    *(bf16x8*)&Asm[0][arow * 64 + (((ach + 1) ^ asw) * 8)] = p1;
  }
  __syncthreads();

  for (int ks = 0; ks < 8; ks++) {
    const int p = ks & 1, pn = p ^ 1;
    float4 xr0, xr1, xr2, xr3;
    // ---- issue prefetch of step ks+1 into buffer pn ----
    if (ks < 7) {
      const int k0n = (ks + 1) * 64;
      if (XMODE == 0) {
        const float* src = Xf + (size_t)(m0 + arow) * DM + k0n + aseg;
        xr0 = *(const float4*)(src);
        xr1 = *(const float4*)(src + 4);
        xr2 = *(const float4*)(src + 8);
        xr3 = *(const float4*)(src + 12);
      } else {
#pragma unroll
        for (int j = 0; j < 2; j++) {
          const int row = j * 32 + w * 8 + l8;
          GLL(Xb + (size_t)(m0 + row) * DM + k0n + swcol,
              &Asm[pn][(j * 256 + w * 64) * 8]);
        }
      }
#pragma unroll
      for (int j = 0; j < 4; j++) {
        const int row = j * 32 + w * 8 + l8;
        GLL(Wm + (size_t)(n0 + row) * DM + k0n + swcol,
            &Bsm[pn][(j * 256 + w * 64) * 8]);
      }
    }

    // ---- compute on buffer p ----
#pragma unroll
    for (int kd = 0; kd < 2; kd++) {
      const int fch = (((kd << 2) + quad) ^ (l15 & 7)) << 3;
      bf16x8 bfr[4];
#pragma unroll
      for (int nb = 0; nb < 4; nb++)
        bfr[nb] = *(const bf16x8*)&Bsm[p][(noff + nb * 16 + l15) * 64 + fch];
#pragma unroll
      for (int mb = 0; mb < 2; mb++) {
        bf16x8 a = *(const bf16x8*)&Asm[p][(moff + mb * 16 + l15) * 64 + fch];
#pragma unroll
        for (int nb = 0; nb < 4; nb++) acc[mb][nb] = MFMA16(a, bfr[nb], acc[mb][nb]);
      }
    }

    // ---- convert + write prefetched fp32 A (loads had MFMA-phase to land) --
    if (XMODE == 0 && ks < 7) {
      bf16x8 p0, p1;
      p0[0] = (bf16_t)xr0.x; p0[1] = (bf16_t)xr0.y; p0[2] = (bf16_t)xr0.z; p0[3] = (bf16_t)xr0.w;
      p0[4] = (bf16_t)xr1.x; p0[5] = (bf16_t)xr1.y; p0[6] = (bf16_t)xr1.z; p0[7] = (bf16_t)xr1.w;
      p1[0] = (bf16_t)xr2.x; p1[1] = (bf16_t)xr2.y; p1[2] = (bf16_t)xr2.z; p1[3] = (bf16_t)xr2.w;
      p1[4] = (bf16_t)xr3.x; p1[5] = (bf16_t)xr3.y; p1[6] = (bf16_t)xr3.z; p1[7] = (bf16_t)xr3.w;
      *(bf16x8*)&Asm[pn][arow * 64 + ((ach ^ asw) * 8)] = p0;
      *(bf16x8*)&Asm[pn][arow * 64 + (((ach + 1) ^ asw) * 8)] = p1;
    }
    __syncthreads();
  }

  // ---- epilogue ----
#pragma unroll
  for (int nb = 0; nb < 4; nb++) {
    const int n = n0 + noff + nb * 16 + l15;
    const float bn = bias[n];
    const int h = n >> 6, dd = n & 63;
#pragma unroll
    for (int mb = 0; mb < 2; mb++) {
      const int mbase = m0 + moff + mb * 16 + quad * 4;
      const int bb = mbase >> 12, s = mbase & 4095;
      if (omode == 0) {
#pragma unroll
        for (int r = 0; r < 4; r++) {
          const float val = (acc[mb][nb][r] + bn) * scale;
          ((bf16_t*)Out)[(size_t)((bb * NH + h) * SEQ + s + r) * HD + dd] = (bf16_t)val;
        }
      } else if (omode == 1) {
        bf16x4 pk;
#pragma unroll
        for (int r = 0; r < 4; r++) pk[r] = (bf16_t)(acc[mb][nb][r] + bn);
        *(bf16x4*)&((bf16_t*)Out)[(((size_t)(bb * NH + h) * HD + dd) << 12) + s] = pk;
      } else {
#pragma unroll
        for (int r = 0; r < 4; r++)
          ((float*)Out)[(size_t)(mbase + r) * DM + n] = acc[mb][nb][r] + bn;
      }
    }
  }
}

// Fused QKV projection. Grid (128,4,3) = 1536 blocks -> 3 blocks/CU.
__global__ __launch_bounds__(256, 3) void qkv_kernel(
    const float* __restrict__ q, const float* __restrict__ k,
    const float* __restrict__ v, const bf16_t* __restrict__ Wall,
    const float* __restrict__ bq, const float* __restrict__ bk,
    const float* __restrict__ bv, bf16_t* __restrict__ Qb,
    bf16_t* __restrict__ Kb, bf16_t* __restrict__ Vb, float qscale) {
  const int z = blockIdx.z;
  const float* X = (z == 0) ? q : (z == 1) ? k : v;
  const float* bias = (z == 0) ? bq : (z == 1) ? bk : bv;
  bf16_t* Out = (z == 0) ? Qb : (z == 1) ? Kb : Vb;
  gemm_body64<0>(X, Wall + (size_t)z * DM * DM, bias, Out,
                 (z == 2) ? 1 : 0, (z == 0) ? qscale : 1.0f);
}

// Output projection. Grid (128,4) = 512 blocks.
__global__ __launch_bounds__(256, 3) void oproj_kernel(
    const bf16_t* __restrict__ X, const bf16_t* __restrict__ Wm,
    const float* __restrict__ bias, float* __restrict__ Out) {
  gemm_body64<1>(X, Wm, bias, Out, 2, 1.0f);
}

// ---------------------------------------------------------------------------
// Flash attention v4: LDS-staged K/V with DOUBLE BUFFER + single barrier/iter.
// GLLs for tile t+1 issue at loop top (full compute-phase in flight), barrier
// at loop end drains them. XOR-swizzled K/V and P tiles (conflict-free b128).
// Fixed-shift softmax p = exp2(s + rb - 16); per-tile const folded into the
// QK accumulator init; row-sum l via ones-MFMA. 32 q/wave, 128 q/block.
// Grid (32,16).
// ---------------------------------------------------------------------------
__global__ __launch_bounds__(256, 2) void attn_kernel(
    const bf16_t* __restrict__ Qb, const bf16_t* __restrict__ Kb,
    const bf16_t* __restrict__ Vb, const float* __restrict__ rel_pos,
    bf16_t* __restrict__ attn_out) {
  __shared__ bf16_t Kt[2][64 * 64];    // swizzled [kk][d], double-buffered
  __shared__ bf16_t Vt[2][64 * 64];    // swizzled [d][kk], double-buffered
  __shared__ bf16_t Pt[4][32 * 64];    // per-wave swizzled P^T [q][kk]

  const int tid = threadIdx.x;
  const int w = tid >> 6;
  const int lane = tid & 63;
  const int quad = lane >> 4, l15 = lane & 15;
  const int bh = blockIdx.y;
  const int b = bh >> 3, h = bh & 7;
  const int qlo = blockIdx.x * 128 + w * 32;

  const float rb0 = rel_pos[h * 5 + 0] * LOG2E;
  const float rb1 = rel_pos[h * 5 + 1] * LOG2E;
  const float rb2 = rel_pos[h * 5 + 2] * LOG2E;
  const float rb3 = rel_pos[h * 5 + 3] * LOG2E;
  const float rb4 = rel_pos[h * 5 + 4] * LOG2E;

  // Q fragments (B-operand): two q-groups of 16
  bf16x8 qf[2][2];
#pragma unroll
  for (int mb = 0; mb < 2; mb++)
#pragma unroll
    for (int kd = 0; kd < 2; kd++)
      qf[mb][kd] = *(const bf16x8*)(Qb + (size_t)(bh * SEQ + qlo + mb * 16 + l15) * HD + kd * 32 + 8 * quad);

  f32x4 o[2][4];
#pragma unroll
  for (int mb = 0; mb < 2; mb++)
#pragma unroll
    for (int db = 0; db < 4; db++) { o[mb][db][0] = 0.f; o[mb][db][1] = 0.f; o[mb][db][2] = 0.f; o[mb][db][3] = 0.f; }
  f32x4 l4[2];
  l4[0][0] = 0.f; l4[0][1] = 0.f; l4[0][2] = 0.f; l4[0][3] = 0.f;
  l4[1][0] = 0.f; l4[1][1] = 0.f; l4[1][2] = 0.f; l4[1][3] = 0.f;

  bf16x8 ones;
#pragma unroll
  for (int i = 0; i < 8; i++) ones[i] = (bf16_t)1.0f;

  // --- staging addresses (swizzled): phys chunk = logical ^ (row&7)
  const int srow = (w << 4) + (lane >> 3);
  const int scol = (((lane & 7) ^ (lane >> 3)) << 3);
  const bf16_t* kg0 = Kb + ((size_t)(bh * SEQ + srow) << 6) + scol;
  const bf16_t* vg0 = Vb + (((size_t)(bh * HD + srow)) << 12) + scol;
  const int ldst = (w << 10);  // wave's LDS dest (elems)

  // --- fragment read bases (swizzled)
  const int sw = l15 & 7;
  const int kfo0 = (l15 << 6) + ((quad ^ sw) << 3);
  const int kfo1 = (l15 << 6) + (((quad + 4) ^ sw) << 3);

  // ---- stage tile 0 into buffer 0 ----
  GLL(kg0, &Kt[0][ldst]);
  GLL(kg0 + (8 << 6), &Kt[0][ldst + 512]);
  GLL(vg0, &Vt[0][ldst]);
  GLL(vg0 + (8 << 12), &Vt[0][ldst + 512]);
  __syncthreads();

  for (int t = 0; t < 64; t++) {
    const int p = t & 1, pn = p ^ 1;
    const int kk0 = t * 64;

    // ---- issue prefetch of tile t+1 into buffer pn (in flight all iter) ----
    const int tg = (t < 63) ? t + 1 : 63;
    GLL(kg0 + ((size_t)tg << 12), &Kt[pn][ldst]);
    GLL(kg0 + ((size_t)tg << 12) + (8 << 6), &Kt[pn][ldst + 512]);
    GLL(vg0 + (tg << 6), &Vt[pn][ldst]);
    GLL(vg0 + (tg << 6) + (8 << 12), &Vt[pn][ldst + 512]);

    // ---- tile class: fold bias const + fixed shift into acc init ----
    float cini;
    bool nearband = false;
    if (kk0 >= qlo + 33) {
      cini = rb4 - SHIFT;
    } else if (kk0 + 63 <= qlo - 2) {
      cini = rb0 - SHIFT;
    } else {
      cini = -SHIFT;
      nearband = true;
    }

    // ---- S^T = K·Q^T ----
    f32x4 s[2][4];
#pragma unroll
    for (int mb = 0; mb < 2; mb++)
#pragma unroll
      for (int kb = 0; kb < 4; kb++) { s[mb][kb][0] = cini; s[mb][kb][1] = cini; s[mb][kb][2] = cini; s[mb][kb][3] = cini; }
#pragma unroll
    for (int kb = 0; kb < 4; kb++) {
      bf16x8 kA0 = *(const bf16x8*)&Kt[p][kfo0 + (kb << 10)];
      bf16x8 kA1 = *(const bf16x8*)&Kt[p][kfo1 + (kb << 10)];
      s[0][kb] = MFMA16(kA0, qf[0][0], s[0][kb]);
      s[0][kb] = MFMA16(kA1, qf[0][1], s[0][kb]);
      s[1][kb] = MFMA16(kA0, qf[1][0], s[1][kb]);
      s[1][kb] = MFMA16(kA1, qf[1][1], s[1][kb]);
    }

    if (nearband) {
#pragma unroll
      for (int mb = 0; mb < 2; mb++) {
        const int qg = qlo + mb * 16 + l15;
#pragma unroll
        for (int kb = 0; kb < 4; kb++)
#pragma unroll
          for (int r = 0; r < 4; r++) {
            int dl = kk0 + kb * 16 + quad * 4 + r - qg;
            float bias = dl <= -2 ? rb0
                       : (dl >= 2 ? rb4
                       : (dl == -1 ? rb1 : (dl == 0 ? rb2 : rb3)));
            s[mb][kb][r] += bias;
          }
      }
    }

    // ---- p = exp2(s) -> swizzled P^T (per-wave region, no barrier) ----
#pragma unroll
    for (int mb = 0; mb < 2; mb++) {
      bf16_t* Pr = &Pt[w][(mb * 16 + l15) * 64];
#pragma unroll
      for (int kb = 0; kb < 4; kb++) {
        bf16x4 pk;
#pragma unroll
        for (int r = 0; r < 4; r++)
          pk[r] = (bf16_t)__builtin_amdgcn_exp2f(s[mb][kb][r]);
        *(bf16x4*)&Pr[(((kb * 2 + (quad >> 1)) ^ sw) << 3) + ((quad & 1) << 2)] = pk;
      }
    }

    // ---- P fragments, l via ones-MFMA, O^T += V^T·P^T ----
    bf16x8 pf[2][2];
#pragma unroll
    for (int mb = 0; mb < 2; mb++)
#pragma unroll
      for (int kc = 0; kc < 2; kc++)
        pf[mb][kc] = *(const bf16x8*)&Pt[w][(mb * 16 + l15) * 64 + ((((kc << 2) + quad) ^ sw) << 3)];

    l4[0] = MFMA16(ones, pf[0][0], l4[0]);
    l4[0] = MFMA16(ones, pf[0][1], l4[0]);
    l4[1] = MFMA16(ones, pf[1][0], l4[1]);
    l4[1] = MFMA16(ones, pf[1][1], l4[1]);

#pragma unroll
    for (int db = 0; db < 4; db++) {
      bf16x8 vA0 = *(const bf16x8*)&Vt[p][kfo0 + (db << 10)];
      bf16x8 vA1 = *(const bf16x8*)&Vt[p][kfo1 + (db << 10)];
      o[0][db] = MFMA16(vA0, pf[0][0], o[0][db]);
      o[0][db] = MFMA16(vA1, pf[0][1], o[0][db]);
      o[1][db] = MFMA16(vA0, pf[1][0], o[1][db]);
      o[1][db] = MFMA16(vA1, pf[1][1], o[1][db]);
    }

    __syncthreads();  // drains prefetch GLLs; all waves done reading buf p
  }

  // ---- epilogue: O^T / l ----
#pragma unroll
  for (int mb = 0; mb < 2; mb++) {
    const float inv = 1.0f / l4[mb][0];
    const int qg = qlo + mb * 16 + l15;
#pragma unroll
    for (int db = 0; db < 4; db++) {
      bf16x4 pk;
#pragma unroll
      for (int r = 0; r < 4; r++) pk[r] = (bf16_t)(o[mb][db][r] * inv);
      *(bf16x4*)(attn_out + (size_t)(b * SEQ + qg) * DM + h * HD + db * 16 + quad * 4) = pk;
    }
  }
}

// ---------------------------------------------------------------------------
extern "C" void kernel_launch(void* const* d_in, const int* in_sizes, int n_in,
                              void* d_out, int out_size, void* d_ws, size_t ws_size,
                              hipStream_t stream) {
  const float* q   = (const float*)d_in[0];
  const float* k   = (const float*)d_in[1];
  const float* v   = (const float*)d_in[2];
  const float* Wq  = (const float*)d_in[3];
  const float* bq  = (const float*)d_in[4];
  const float* Wk  = (const float*)d_in[5];
  const float* bk  = (const float*)d_in[6];
  const float* Wv  = (const float*)d_in[7];
  const float* bv  = (const float*)d_in[8];
  const float* Wo  = (const float*)d_in[9];
  const float* bo  = (const float*)d_in[10];
  const float* rel = (const float*)d_in[11];

  char* ws = (char*)d_ws;
  bf16_t* Wbf  = (bf16_t*)ws;                               // 2MB (4 matrices)
  bf16_t* Qbuf = (bf16_t*)(ws + (size_t)(2  << 20));        // 8MB [bh][s][64]
  bf16_t* Kbuf = (bf16_t*)(ws + (size_t)(10 << 20));        // 8MB [bh][s][64]
  bf16_t* Vbuf = (bf16_t*)(ws + (size_t)(18 << 20));        // 8MB [bh][d][s]
  bf16_t* Abuf = (bf16_t*)(ws + (size_t)(26 << 20));        // 8MB [b][s][512]

  cvt_w_kernel<<<dim3(256, 4), 256, 0, stream>>>(Wq, Wk, Wv, Wo, Wbf);

  const float qscale = LOG2E / 8.0f;  // fold 1/sqrt(64) + exp2 domain
  qkv_kernel<<<dim3(128, 4, 3), 256, 0, stream>>>(
      q, k, v, Wbf, bq, bk, bv, Qbuf, Kbuf, Vbuf, qscale);

  attn_kernel<<<dim3(32, 16), 256, 0, stream>>>(Qbuf, Kbuf, Vbuf, rel, Abuf);

  oproj_kernel<<<dim3(128, 4), 256, 0, stream>>>(Abuf, Wbf + 3 * DM * DM, bo, (float*)d_out);
}

// Round 8
// 239.651 us; speedup vs baseline: 1.1493x; 1.0050x over previous
//
#include <hip/hip_runtime.h>

typedef __bf16 bf16_t;
typedef __bf16 bf16x4 __attribute__((ext_vector_type(4)));
typedef __bf16 bf16x8 __attribute__((ext_vector_type(8)));
typedef float f32x4 __attribute__((ext_vector_type(4)));

#define MFMA16(a, b, c) __builtin_amdgcn_mfma_f32_16x16x32_bf16(a, b, c, 0, 0, 0)
#define LOG2E 1.4426950408889634f
#define SHIFT 16.0f

// async global -> LDS, 16B per lane (LDS dest = wave-uniform base + lane*16)
#define GLL(g, l)                                                      \
  __builtin_amdgcn_global_load_lds(                                    \
      (const __attribute__((address_space(1))) void*)(g),              \
      (__attribute__((address_space(3))) void*)(l), 16, 0, 0)

// raw barrier: wait only the OLDEST in-flight GLLs (newest stay in flight),
// then s_barrier WITHOUT the compiler's vmcnt(0) drain.
#define WAIT_BARRIER_V4() asm volatile("s_waitcnt vmcnt(4)\n\ts_barrier" ::: "memory")
#define WAIT_BARRIER_V6() asm volatile("s_waitcnt vmcnt(6)\n\ts_barrier" ::: "memory")

static constexpr int NB = 2;
static constexpr int SEQ = 4096;
static constexpr int DM = 512;
static constexpr int NH = 8;
static constexpr int HD = 64;
static constexpr int M_ROWS = NB * SEQ;  // 8192

// ---------------------------------------------------------------------------
// Weights fp32 -> bf16
// ---------------------------------------------------------------------------
__global__ __launch_bounds__(256) void cvt_w_kernel(
    const float* __restrict__ w0, const float* __restrict__ w1,
    const float* __restrict__ w2, const float* __restrict__ w3,
    bf16_t* __restrict__ out) {
  const float* src = (blockIdx.y == 0) ? w0 : (blockIdx.y == 1) ? w1
                   : (blockIdx.y == 2) ? w2 : w3;
  int i = (blockIdx.x * 256 + threadIdx.x) * 4;
  float4 v = *(const float4*)(src + i);
  bf16_t* o = out + blockIdx.y * (DM * DM) + i;
  o[0] = (bf16_t)v.x; o[1] = (bf16_t)v.y; o[2] = (bf16_t)v.z; o[3] = (bf16_t)v.w;
}

// ---------------------------------------------------------------------------
// Inputs q,k,v fp32 -> bf16 (fused)
// ---------------------------------------------------------------------------
__global__ __launch_bounds__(256) void cvt_x_kernel(
    const float* __restrict__ q, const float* __restrict__ k,
    const float* __restrict__ v, bf16_t* __restrict__ out) {
  const float* src = (blockIdx.y == 0) ? q : (blockIdx.y == 1) ? k : v;
  bf16_t* dst = out + (size_t)blockIdx.y * (M_ROWS * DM);
  int i = (blockIdx.x * 256 + threadIdx.x) * 8;
  float4 a = *(const float4*)(src + i);
  float4 b = *(const float4*)(src + i + 4);
  bf16x8 o;
  o[0] = (bf16_t)a.x; o[1] = (bf16_t)a.y; o[2] = (bf16_t)a.z; o[3] = (bf16_t)a.w;
  o[4] = (bf16_t)b.x; o[5] = (bf16_t)b.y; o[6] = (bf16_t)b.z; o[7] = (bf16_t)b.w;
  *(bf16x8*)(dst + i) = o;
}

// ---------------------------------------------------------------------------
// GEMM v4: Out = (X @ W^T + bias) * scale. Tile 64x128, BK=64, 3-stage LDS
// pipeline with raw-barrier async: per K-step wait only the oldest 6 GLLs
// (vmcnt(6)), raw s_barrier, issue step ks+2 into the buffer freed by ks-1,
// compute step ks. XOR-swizzled LDS (16B chunks, phys = ch ^ (row&7)).
// omode 0: bf16 [bh][s][64]; 1: bf16 [bh][d][s]; 2: fp32 [m][512].
// ---------------------------------------------------------------------------
__device__ __forceinline__ void gemm_body64(
    const bf16_t* __restrict__ X, const bf16_t* __restrict__ Wm,
    const float* __restrict__ bias, void* __restrict__ Out,
    int omode, float scale) {
  __shared__ bf16_t Asm[3][64 * 64];
  __shared__ bf16_t Bsm[3][128 * 64];

  const int tid = threadIdx.x;
  const int w = tid >> 6;
  const int lane = tid & 63;
  const int quad = lane >> 4, l15 = lane & 15;
  const int l8 = lane >> 3;
  const int swcol = ((lane & 7) ^ l8) * 8;  // swizzled source col (elems)
  const int m0 = blockIdx.x * 64;
  const int n0 = blockIdx.y * 128;
  const int moff = (w & 1) * 32;
  const int noff = (w >> 1) * 64;

  f32x4 acc[2][4];
#pragma unroll
  for (int mb = 0; mb < 2; mb++)
#pragma unroll
    for (int nb = 0; nb < 4; nb++) { acc[mb][nb][0] = 0.f; acc[mb][nb][1] = 0.f; acc[mb][nb][2] = 0.f; acc[mb][nb][3] = 0.f; }

  // stage K-step ks into LDS buffer bufi (6 GLLs per thread: 4 B + 2 A)
  auto stage = [&](int ks, int bufi) {
    const int k0 = ks * 64;
#pragma unroll
    for (int j = 0; j < 4; j++) {
      const int row = j * 32 + w * 8 + l8;
      GLL(Wm + (size_t)(n0 + row) * DM + k0 + swcol, &Bsm[bufi][(j * 256 + w * 64) * 8]);
    }
#pragma unroll
    for (int j = 0; j < 2; j++) {
      const int row = j * 32 + w * 8 + l8;
      GLL(X + (size_t)(m0 + row) * DM + k0 + swcol, &Asm[bufi][(j * 256 + w * 64) * 8]);
    }
  };

  stage(0, 0);
  stage(1, 1);

  for (int ks = 0; ks < 8; ks++) {
    WAIT_BARRIER_V6();             // step-ks tile landed everywhere; buffer
                                   // (ks-1)%3 free for reuse
    const int tn = (ks + 2 < 8) ? ks + 2 : 7;   // dummy re-issue keeps counts uniform
    stage(tn, (ks + 2) % 3);
    const int p = ks % 3;

#pragma unroll
    for (int kd = 0; kd < 2; kd++) {
      const int fch = (((kd << 2) + quad) ^ (l15 & 7)) << 3;
      bf16x8 bfr[4];
#pragma unroll
      for (int nb = 0; nb < 4; nb++)
        bfr[nb] = *(const bf16x8*)&Bsm[p][(noff + nb * 16 + l15) * 64 + fch];
#pragma unroll
      for (int mb = 0; mb < 2; mb++) {
        bf16x8 a = *(const bf16x8*)&Asm[p][(moff + mb * 16 + l15) * 64 + fch];
#pragma unroll
        for (int nb = 0; nb < 4; nb++) acc[mb][nb] = MFMA16(a, bfr[nb], acc[mb][nb]);
      }
    }
  }

  // ---- epilogue ----
#pragma unroll
  for (int nb = 0; nb < 4; nb++) {
    const int n = n0 + noff + nb * 16 + l15;
    const float bn = bias[n];
    const int h = n >> 6, dd = n & 63;
#pragma unroll
    for (int mb = 0; mb < 2; mb++) {
      const int mbase = m0 + moff + mb * 16 + quad * 4;
      const int bb = mbase >> 12, s = mbase & 4095;
      if (omode == 0) {
#pragma unroll
        for (int r = 0; r < 4; r++) {
          const float val = (acc[mb][nb][r] + bn) * scale;
          ((bf16_t*)Out)[(size_t)((bb * NH + h) * SEQ + s + r) * HD + dd] = (bf16_t)val;
        }
      } else if (omode == 1) {
        bf16x4 pk;
#pragma unroll
        for (int r = 0; r < 4; r++) pk[r] = (bf16_t)(acc[mb][nb][r] + bn);
        *(bf16x4*)&((bf16_t*)Out)[(((size_t)(bb * NH + h) * HD + dd) << 12) + s] = pk;
      } else {
#pragma unroll
        for (int r = 0; r < 4; r++)
          ((float*)Out)[(size_t)(mbase + r) * DM + n] = acc[mb][nb][r] + bn;
      }
    }
  }
}

// Fused QKV projection (bf16 inputs). Grid (128,4,3).
__global__ __launch_bounds__(256, 2) void qkv_kernel(
    const bf16_t* __restrict__ Xall, const bf16_t* __restrict__ Wall,
    const float* __restrict__ bq, const float* __restrict__ bk,
    const float* __restrict__ bv, bf16_t* __restrict__ Qb,
    bf16_t* __restrict__ Kb, bf16_t* __restrict__ Vb, float qscale) {
  const int z = blockIdx.z;
  const bf16_t* X = Xall + (size_t)z * (M_ROWS * DM);
  const float* bias = (z == 0) ? bq : (z == 1) ? bk : bv;
  bf16_t* Out = (z == 0) ? Qb : (z == 1) ? Kb : Vb;
  gemm_body64(X, Wall + (size_t)z * DM * DM, bias, Out,
              (z == 2) ? 1 : 0, (z == 0) ? qscale : 1.0f);
}

// Output projection. Grid (128,4).
__global__ __launch_bounds__(256, 2) void oproj_kernel(
    const bf16_t* __restrict__ X, const bf16_t* __restrict__ Wm,
    const float* __restrict__ bias, float* __restrict__ Out) {
  gemm_body64(X, Wm, bias, Out, 2, 1.0f);
}

// ---------------------------------------------------------------------------
// Flash attention v5: 3-stage K/V LDS pipeline with raw-barrier async.
// Per iter: wait vmcnt(4) (tile t landed; tile t+1 stays in flight), raw
// s_barrier, issue tile t+2 into the buffer freed by tile t-1, compute t.
// Fixed-shift softmax p = exp2(s + rb - 16), bias const folded into QK acc
// init, row-sum l via ones-MFMA, per-wave swizzled P^T round-trip.
// 32 q/wave, 128 q/block. Grid (32,16).
// ---------------------------------------------------------------------------
__global__ __launch_bounds__(256, 2) void attn_kernel(
    const bf16_t* __restrict__ Qb, const bf16_t* __restrict__ Kb,
    const bf16_t* __restrict__ Vb, const float* __restrict__ rel_pos,
    bf16_t* __restrict__ attn_out) {
  __shared__ bf16_t Kt[3][64 * 64];    // swizzled [kk][d], 3-stage
  __shared__ bf16_t Vt[3][64 * 64];    // swizzled [d][kk], 3-stage
  __shared__ bf16_t Pt[4][32 * 64];    // per-wave swizzled P^T [q][kk]

  const int tid = threadIdx.x;
  const int w = tid >> 6;
  const int lane = tid & 63;
  const int quad = lane >> 4, l15 = lane & 15;
  const int bh = blockIdx.y;
  const int b = bh >> 3, h = bh & 7;
  const int qlo = blockIdx.x * 128 + w * 32;

  const float rb0 = rel_pos[h * 5 + 0] * LOG2E;
  const float rb1 = rel_pos[h * 5 + 1] * LOG2E;
  const float rb2 = rel_pos[h * 5 + 2] * LOG2E;
  const float rb3 = rel_pos[h * 5 + 3] * LOG2E;
  const float rb4 = rel_pos[h * 5 + 4] * LOG2E;

  // Q fragments (B-operand): two q-groups of 16
  bf16x8 qf[2][2];
#pragma unroll
  for (int mb = 0; mb < 2; mb++)
#pragma unroll
    for (int kd = 0; kd < 2; kd++)
      qf[mb][kd] = *(const bf16x8*)(Qb + (size_t)(bh * SEQ + qlo + mb * 16 + l15) * HD + kd * 32 + 8 * quad);

  f32x4 o[2][4];
#pragma unroll
  for (int mb = 0; mb < 2; mb++)
#pragma unroll
    for (int db = 0; db < 4; db++) { o[mb][db][0] = 0.f; o[mb][db][1] = 0.f; o[mb][db][2] = 0.f; o[mb][db][3] = 0.f; }
  f32x4 l4[2];
  l4[0][0] = 0.f; l4[0][1] = 0.f; l4[0][2] = 0.f; l4[0][3] = 0.f;
  l4[1][0] = 0.f; l4[1][1] = 0.f; l4[1][2] = 0.f; l4[1][3] = 0.f;

  bf16x8 ones;
#pragma unroll
  for (int i = 0; i < 8; i++) ones[i] = (bf16_t)1.0f;

  // --- staging addresses (swizzled): phys chunk = logical ^ (row&7)
  const int srow = (w << 4) + (lane >> 3);
  const int scol = (((lane & 7) ^ (lane >> 3)) << 3);
  const bf16_t* kg0 = Kb + ((size_t)(bh * SEQ + srow) << 6) + scol;
  const bf16_t* vg0 = Vb + (((size_t)(bh * HD + srow)) << 12) + scol;
  const int ldst = (w << 10);  // wave's LDS dest (elems)

  // --- fragment read bases (swizzled)
  const int sw = l15 & 7;
  const int kfo0 = (l15 << 6) + ((quad ^ sw) << 3);
  const int kfo1 = (l15 << 6) + (((quad + 4) ^ sw) << 3);

  auto stage = [&](int t, int bufi) {
    GLL(kg0 + ((size_t)t << 12), &Kt[bufi][ldst]);
    GLL(kg0 + ((size_t)t << 12) + (8 << 6), &Kt[bufi][ldst + 512]);
    GLL(vg0 + (t << 6), &Vt[bufi][ldst]);
    GLL(vg0 + (t << 6) + (8 << 12), &Vt[bufi][ldst + 512]);
  };

  stage(0, 0);
  stage(1, 1);

  for (int t = 0; t < 64; t++) {
    WAIT_BARRIER_V4();             // tile t landed everywhere; buffer (t-1)%3 free
    const int tg = (t + 2 < 64) ? t + 2 : 63;
    stage(tg, (t + 2) % 3);
    const int p = t % 3;
    const int kk0 = t * 64;

    // ---- tile class: fold bias const + fixed shift into acc init ----
    float cini;
    bool nearband = false;
    if (kk0 >= qlo + 33) {
      cini = rb4 - SHIFT;
    } else if (kk0 + 63 <= qlo - 2) {
      cini = rb0 - SHIFT;
    } else {
      cini = -SHIFT;
      nearband = true;
    }

    // ---- S^T = K·Q^T ----
    f32x4 s[2][4];
#pragma unroll
    for (int mb = 0; mb < 2; mb++)
#pragma unroll
      for (int kb = 0; kb < 4; kb++) { s[mb][kb][0] = cini; s[mb][kb][1] = cini; s[mb][kb][2] = cini; s[mb][kb][3] = cini; }
#pragma unroll
    for (int kb = 0; kb < 4; kb++) {
      bf16x8 kA0 = *(const bf16x8*)&Kt[p][kfo0 + (kb << 10)];
      bf16x8 kA1 = *(const bf16x8*)&Kt[p][kfo1 + (kb << 10)];
      s[0][kb] = MFMA16(kA0, qf[0][0], s[0][kb]);
      s[0][kb] = MFMA16(kA1, qf[0][1], s[0][kb]);
      s[1][kb] = MFMA16(kA0, qf[1][0], s[1][kb]);
      s[1][kb] = MFMA16(kA1, qf[1][1], s[1][kb]);
    }

    if (nearband) {
#pragma unroll
      for (int mb = 0; mb < 2; mb++) {
        const int qg = qlo + mb * 16 + l15;
#pragma unroll
        for (int kb = 0; kb < 4; kb++)
#pragma unroll
          for (int r = 0; r < 4; r++) {
            int dl = kk0 + kb * 16 + quad * 4 + r - qg;
            float bias = dl <= -2 ? rb0
                       : (dl >= 2 ? rb4
                       : (dl == -1 ? rb1 : (dl == 0 ? rb2 : rb3)));
            s[mb][kb][r] += bias;
          }
      }
    }

    // ---- p = exp2(s) -> swizzled P^T (per-wave region, no barrier) ----
#pragma unroll
    for (int mb = 0; mb < 2; mb++) {
      bf16_t* Pr = &Pt[w][(mb * 16 + l15) * 64];
#pragma unroll
      for (int kb = 0; kb < 4; kb++) {
        bf16x4 pk;
#pragma unroll
        for (int r = 0; r < 4; r++)
          pk[r] = (bf16_t)__builtin_amdgcn_exp2f(s[mb][kb][r]);
        *(bf16x4*)&Pr[(((kb * 2 + (quad >> 1)) ^ sw) << 3) + ((quad & 1) << 2)] = pk;
      }
    }

    // ---- P fragments, l via ones-MFMA, O^T += V^T·P^T ----
    bf16x8 pf[2][2];
#pragma unroll
    for (int mb = 0; mb < 2; mb++)
#pragma unroll
      for (int kc = 0; kc < 2; kc++)
        pf[mb][kc] = *(const bf16x8*)&Pt[w][(mb * 16 + l15) * 64 + ((((kc << 2) + quad) ^ sw) << 3)];

    l4[0] = MFMA16(ones, pf[0][0], l4[0]);
    l4[0] = MFMA16(ones, pf[0][1], l4[0]);
    l4[1] = MFMA16(ones, pf[1][0], l4[1]);
    l4[1] = MFMA16(ones, pf[1][1], l4[1]);

#pragma unroll
    for (int db = 0; db < 4; db++) {
      bf16x8 vA0 = *(const bf16x8*)&Vt[p][kfo0 + (db << 10)];
      bf16x8 vA1 = *(const bf16x8*)&Vt[p][kfo1 + (db << 10)];
      o[0][db] = MFMA16(vA0, pf[0][0], o[0][db]);
      o[0][db] = MFMA16(vA1, pf[0][1], o[0][db]);
      o[1][db] = MFMA16(vA0, pf[1][0], o[1][db]);
      o[1][db] = MFMA16(vA1, pf[1][1], o[1][db]);
    }
  }

  // ---- epilogue: O^T / l ----
#pragma unroll
  for (int mb = 0; mb < 2; mb++) {
    const float inv = 1.0f / l4[mb][0];
    const int qg = qlo + mb * 16 + l15;
#pragma unroll
    for (int db = 0; db < 4; db++) {
      bf16x4 pk;
#pragma unroll
      for (int r = 0; r < 4; r++) pk[r] = (bf16_t)(o[mb][db][r] * inv);
      *(bf16x4*)(attn_out + (size_t)(b * SEQ + qg) * DM + h * HD + db * 16 + quad * 4) = pk;
    }
  }
}

// ---------------------------------------------------------------------------
extern "C" void kernel_launch(void* const* d_in, const int* in_sizes, int n_in,
                              void* d_out, int out_size, void* d_ws, size_t ws_size,
                              hipStream_t stream) {
  const float* q   = (const float*)d_in[0];
  const float* k   = (const float*)d_in[1];
  const float* v   = (const float*)d_in[2];
  const float* Wq  = (const float*)d_in[3];
  const float* bq  = (const float*)d_in[4];
  const float* Wk  = (const float*)d_in[5];
  const float* bk  = (const float*)d_in[6];
  const float* Wv  = (const float*)d_in[7];
  const float* bv  = (const float*)d_in[8];
  const float* Wo  = (const float*)d_in[9];
  const float* bo  = (const float*)d_in[10];
  const float* rel = (const float*)d_in[11];

  char* ws = (char*)d_ws;
  bf16_t* Wbf  = (bf16_t*)ws;                               // 2MB (4 matrices)
  bf16_t* Xb   = (bf16_t*)(ws + (size_t)(2  << 20));        // 24MB bf16 q,k,v
  bf16_t* Qbuf = (bf16_t*)(ws + (size_t)(26 << 20));        // 8MB [bh][s][64]
  bf16_t* Kbuf = (bf16_t*)(ws + (size_t)(34 << 20));        // 8MB [bh][s][64]
  bf16_t* Vbuf = (bf16_t*)(ws + (size_t)(42 << 20));        // 8MB [bh][d][s]
  bf16_t* Abuf = (bf16_t*)(ws + (size_t)(2  << 20));        // alias Xb (dead after qkv)

  cvt_w_kernel<<<dim3(256, 4), 256, 0, stream>>>(Wq, Wk, Wv, Wo, Wbf);
  cvt_x_kernel<<<dim3(2048, 3), 256, 0, stream>>>(q, k, v, Xb);

  const float qscale = LOG2E / 8.0f;  // fold 1/sqrt(64) + exp2 domain
  qkv_kernel<<<dim3(128, 4, 3), 256, 0, stream>>>(
      Xb, Wbf, bq, bk, bv, Qbuf, Kbuf, Vbuf, qscale);

  attn_kernel<<<dim3(32, 16), 256, 0, stream>>>(Qbuf, Kbuf, Vbuf, rel, Abuf);

  oproj_kernel<<<dim3(128, 4), 256, 0, stream>>>(Abuf, Wbf + 3 * DM * DM, bo, (float*)d_out);
}